// Round 5
// baseline (355.704 us; speedup 1.0000x reference)
//
#include <hip/hip_runtime.h>

#define NN 20000

typedef _Float16 f16x4 __attribute__((ext_vector_type(4)));
typedef _Float16 f16x2 __attribute__((ext_vector_type(2)));

// ---------------- softmax of W (single block) ----------------
__global__ __launch_bounds__(1024) void softmax_kernel(const float* __restrict__ W,
                                                       float* __restrict__ pi,
                                                       float* __restrict__ pi1,
                                                       float* __restrict__ pi2) {
    __shared__ float red[1024];
    __shared__ float piL[4096];
    int t = threadIdx.x;
    float4 wv = ((const float4*)W)[t];
    float m = fmaxf(fmaxf(wv.x, wv.y), fmaxf(wv.z, wv.w));
    red[t] = m; __syncthreads();
    for (int s = 512; s > 0; s >>= 1) {
        if (t < s) red[t] = fmaxf(red[t], red[t + s]);
        __syncthreads();
    }
    m = red[0];
    __syncthreads();
    float e0 = expf(wv.x - m), e1 = expf(wv.y - m);
    float e2 = expf(wv.z - m), e3 = expf(wv.w - m);
    red[t] = e0 + e1 + e2 + e3;
    __syncthreads();
    for (int s = 512; s > 0; s >>= 1) {
        if (t < s) red[t] += red[t + s];
        __syncthreads();
    }
    float inv = 1.0f / red[0];
    piL[t * 4 + 0] = e0 * inv;
    piL[t * 4 + 1] = e1 * inv;
    piL[t * 4 + 2] = e2 * inv;
    piL[t * 4 + 3] = e3 * inv;
    pi[t * 4 + 0] = e0 * inv;
    pi[t * 4 + 1] = e1 * inv;
    pi[t * 4 + 2] = e2 * inv;
    pi[t * 4 + 3] = e3 * inv;
    __syncthreads();
    if (t < 64) {            // row sums -> pi1 (weights for F1)
        float s = 0.f;
        for (int k = 0; k < 64; k++) s += piL[t * 64 + k];
        pi1[t] = s;
    } else if (t < 128) {    // col sums -> pi2 (weights for F2)
        int k = t - 64;
        float s = 0.f;
        for (int j = 0; j < 64; j++) s += piL[j * 64 + k];
        pi2[k] = s;
    }
}

// ---------------- pack a0 fp32 (B,N) planes -> f16x4 table ----------------
__global__ __launch_bounds__(1024) void packf16_kernel(const float* __restrict__ a0,
                                                       f16x4* __restrict__ T0) {
    int i = blockIdx.x * 1024 + threadIdx.x;
    if (i < NN) {
        f16x4 h = { (_Float16)a0[i], (_Float16)a0[NN + i],
                    (_Float16)a0[2 * NN + i], (_Float16)a0[3 * NN + i] };
        T0[i] = h;
    }
}

// ---------------- DPP packed-f16 oct-max (VALU pipe) ----------------
__device__ __forceinline__ f16x2 pkmax(f16x2 a, f16x2 b) {
    return __builtin_elementwise_max(a, b);
}
// max over each aligned 8-lane group; all 8 lanes end with the max
__device__ __forceinline__ f16x2 oct_max(f16x2 v) {
    union { f16x2 h; int i; } a, b;
    a.h = v;
    b.i = __builtin_amdgcn_update_dpp(0, a.i, 0xB1, 0xF, 0xF, true);   // quad xor1
    a.h = pkmax(a.h, b.h);
    b.i = __builtin_amdgcn_update_dpp(0, a.i, 0x4E, 0xF, 0xF, true);   // quad xor2
    a.h = pkmax(a.h, b.h);
    b.i = __builtin_amdgcn_update_dpp(0, a.i, 0x141, 0xF, 0xF, true);  // row_half_mirror
    a.h = pkmax(a.h, b.h);
    return a.h;
}

// ---------------- phase 1: F-clause gathers ----------------
// Wave = one (tab,k-octet): lanes (ni,w) = 8 n x 8 w. X loads are 512 B
// contiguous per wave-instr. a-table (f16x4, all 4 b) in 160,000 B static LDS.
// Output: F f16 planes, layout [(tab*4+b)*64 + k][NN].
// TS=0: table from packed f16x4 T; TS=1: table from 4 f16 (B,N) planes.
template <int TS>
__global__ __launch_bounds__(1024) void fclause_kernel(
    const f16x4* __restrict__ Tpk, const _Float16* __restrict__ Tpl,
    const int* __restrict__ X1, const int* __restrict__ X2,
    _Float16* __restrict__ F) {
    __shared__ f16x4 tab_lds[NN];
    const int tid = threadIdx.x;
    if (TS == 0) {
        for (int i = tid; i < NN; i += 1024) tab_lds[i] = Tpk[i];
    } else {
        for (int i = tid; i < NN; i += 1024) {
            f16x4 h = { Tpl[i], Tpl[NN + i], Tpl[2 * NN + i], Tpl[3 * NN + i] };
            tab_lds[i] = h;
        }
    }
    __syncthreads();

    const int wid = tid >> 6, lane = tid & 63;
    const int ni = lane >> 3, w = lane & 7;
    const int tabsel = wid >> 3;        // wave-uniform
    const int kbase = (wid & 7) * 8;
    const int* __restrict__ X = tabsel ? X2 : X1;

    // contiguous n-partition: first 32 blocks 79 n, rest 78 n (no 2-round tail)
    const int bid = (int)blockIdx.x;
    const int nb0 = bid < 32 ? bid * 79 : 32 * 79 + (bid - 32) * 78;
    const int nb1 = nb0 + (bid < 32 ? 79 : 78);

    for (int c = 0; c < 10; ++c) {
        const int n = nb0 + c * 8 + ni;
        const int nc = n < NN ? n : NN - 1;  // clamp loads (last block only)
#pragma unroll
        for (int jl = 0; jl < 8; ++jl) {
            const int k = kbase + jl;
            int2 q = *((const int2*)X + ((size_t)k * NN + nc) * 8 + w);
            f16x4 g0 = tab_lds[q.x];
            f16x4 g1 = tab_lds[q.y];
            f16x4 p = g0 * g1;
            f16x2 lo = { p[0], p[1] }, hi = { p[2], p[3] };
            lo = oct_max(lo);
            hi = oct_max(hi);
            if (w < 4 && n < nb1) {  // lane w stores batch b=w
                _Float16 val = (w == 0) ? lo[0] : (w == 1) ? lo[1]
                             : (w == 2) ? hi[0] : hi[1];
                F[((size_t)((tabsel * 4 + w) * 64 + k)) * NN + n] = val;
            }
        }
    }
}

// ---------------- phase 2: bilinear + soft-OR update ----------------
// Thread = one (n,b). F2[64] resident in VGPRs; pi rows are wave-uniform
// (scalar loads). ITER=1: aprev = exact a0, out = A1 f16 planes.
// ITER=2: aprev = A1, out = fp32 (B,N) planes.
template <int ITER>
__global__ __launch_bounds__(256) void bilinear_kernel(
    const _Float16* __restrict__ F,
    const float* __restrict__ pi, const float* __restrict__ pi1,
    const float* __restrict__ pi2,
    const float* __restrict__ a0, const _Float16* __restrict__ A1,
    _Float16* __restrict__ outA1, float* __restrict__ outP) {
    const int b = (int)blockIdx.y;
    const int n = (int)blockIdx.x * 256 + threadIdx.x;
    if (n >= NN) return;
    const _Float16* F1p = F + ((size_t)(b * 64)) * NN + n;
    const _Float16* F2p = F + ((size_t)((4 + b) * 64)) * NN + n;

    float F2v[64];
#pragma unroll
    for (int k = 0; k < 64; ++k) F2v[k] = (float)F2p[(size_t)k * NN];

    float Ev = 0.f;
#pragma unroll
    for (int k = 0; k < 64; ++k) Ev += pi2[k] * F2v[k];

    float Eu = 0.f, Euv = 0.f;
    for (int j = 0; j < 64; ++j) {
        float f1 = (float)F1p[(size_t)j * NN];
        const float* __restrict__ pr = pi + j * 64;  // wave-uniform -> s_load
        float m0 = 0.f, m1 = 0.f, m2 = 0.f, m3 = 0.f;
#pragma unroll
        for (int k = 0; k < 64; k += 4) {
            m0 += pr[k] * F2v[k];
            m1 += pr[k + 1] * F2v[k + 1];
            m2 += pr[k + 2] * F2v[k + 2];
            m3 += pr[k + 3] * F2v[k + 3];
        }
        Eu += pi1[j] * f1;
        Euv += f1 * ((m0 + m1) + (m2 + m3));
    }
    float d = Eu + Ev - Euv;
    float ap = (ITER == 1) ? a0[(size_t)b * NN + n] : (float)A1[(size_t)b * NN + n];
    float an = 1.0f - (1.0f - ap) * (1.0f - d);
    if (ITER == 1)
        outA1[(size_t)b * NN + n] = (_Float16)an;
    else
        outP[(size_t)b * NN + n] = an;
}

// ================= R4 fallback (known-good, 313 us) =================
__global__ __launch_bounds__(1024) void expand_kernel(const f16x4* __restrict__ src,
                                                      float* __restrict__ out) {
    int t = threadIdx.x;
    f16x4 v[20];
#pragma unroll
    for (int i = 0; i < 20; i++) {
        int idx = i * 1024 + t;
        if (idx < NN) v[i] = src[idx];
    }
    __syncthreads();
#pragma unroll
    for (int i = 0; i < 20; i++) {
        int idx = i * 1024 + t;
        if (idx < NN) {
            out[idx] = (float)v[i][0];
            out[NN + idx] = (float)v[i][1];
            out[2 * NN + idx] = (float)v[i][2];
            out[3 * NN + idx] = (float)v[i][3];
        }
    }
}

__device__ __forceinline__ void compute_F(const int* __restrict__ X,
                                          const f16x4* __restrict__ aldsv,
                                          int n, int l, float4 pw,
                                          float Ff[4][4], float acc[4]) {
#pragma unroll
    for (int kk = 0; kk < 4; ++kk) {
        int k = l * 4 + kk;
        const int4* xq = (const int4*)X + ((size_t)k * NN + n) * 4;
        f16x4 fm = { (_Float16)0, (_Float16)0, (_Float16)0, (_Float16)0 };
#pragma unroll
        for (int ww = 0; ww < 4; ++ww) {
            int4 q = xq[ww];
            f16x4 g0 = aldsv[q.x];
            f16x4 g1 = aldsv[q.y];
            f16x4 g2 = aldsv[q.z];
            f16x4 g3 = aldsv[q.w];
            fm = __builtin_elementwise_max(fm, g0 * g1);
            fm = __builtin_elementwise_max(fm, g2 * g3);
        }
        float pk = (kk == 0) ? pw.x : (kk == 1) ? pw.y : (kk == 2) ? pw.z : pw.w;
#pragma unroll
        for (int b = 0; b < 4; b++) {
            float f = (float)fm[b];
            Ff[kk][b] = f;
            acc[b] += pk * f;
        }
    }
}

template <int SRC16, int DST16>
__global__ __launch_bounds__(1024) void iter_kernel(
    const float* __restrict__ asrc, const f16x4* __restrict__ asrc16,
    const int* __restrict__ X1, const int* __restrict__ X2,
    const float* __restrict__ pi, const float* __restrict__ pi1,
    const float* __restrict__ pi2,
    float* __restrict__ dst, f16x4* __restrict__ dst16) {
    __shared__ f16x4 aldsv[NN];
    int tid = threadIdx.x;
    if (SRC16) {
        for (int i = tid; i < NN; i += 1024) aldsv[i] = asrc16[i];
    } else {
        for (int i = tid; i < NN; i += 1024) {
            f16x4 h = { (_Float16)asrc[i], (_Float16)asrc[NN + i],
                        (_Float16)asrc[2 * NN + i], (_Float16)asrc[3 * NN + i] };
            aldsv[i] = h;
        }
    }
    __syncthreads();
    int l = tid & 15;
    int g = tid >> 4;
    int n = blockIdx.x * 64 + g;
    if (n >= NN) return;
    float4 p1v = ((const float4*)pi1)[l];
    float4 p2v = ((const float4*)pi2)[l];
    float F1f[4][4], F2f[4][4];
    float A1[4] = {0, 0, 0, 0}, Ev[4] = {0, 0, 0, 0}, A2[4] = {0, 0, 0, 0};
    compute_F(X2, aldsv, n, l, p2v, F2f, Ev);
    compute_F(X1, aldsv, n, l, p1v, F1f, A1);
    for (int jo = 0; jo < 16; jo++) {
#pragma unroll
        for (int ji = 0; ji < 4; ji++) {
            int j = jo * 4 + ji;
            float4 pr = ((const float4*)(pi + j * 64))[l];
#pragma unroll
            for (int b = 0; b < 4; b++) {
                float f1 = __shfl(F1f[ji][b], jo, 16);
                float t = pr.x * F2f[0][b] + pr.y * F2f[1][b] +
                          pr.z * F2f[2][b] + pr.w * F2f[3][b];
                A2[b] += f1 * t;
            }
        }
    }
    float s[4];
#pragma unroll
    for (int b = 0; b < 4; b++) s[b] = A1[b] + Ev[b] - A2[b];
#pragma unroll
    for (int off = 8; off >= 1; off >>= 1) {
#pragma unroll
        for (int b = 0; b < 4; b++) s[b] += __shfl_xor(s[b], off, 16);
    }
    if (l == 0) {
        float a[4];
        if (SRC16) {
            f16x4 h = aldsv[n];
#pragma unroll
            for (int b = 0; b < 4; b++) a[b] = (float)h[b];
        } else {
#pragma unroll
            for (int b = 0; b < 4; b++) a[b] = asrc[(size_t)b * NN + n];
        }
#pragma unroll
        for (int b = 0; b < 4; b++) s[b] = 1.0f - (1.0f - a[b]) * (1.0f - s[b]);
        if (DST16) {
            f16x4 h = { (_Float16)s[0], (_Float16)s[1], (_Float16)s[2], (_Float16)s[3] };
            dst16[n] = h;
        } else {
            dst[n] = s[0];
            dst[NN + n] = s[1];
            dst[2 * NN + n] = s[2];
            dst[3 * NN + n] = s[3];
        }
    }
}

extern "C" void kernel_launch(void* const* d_in, const int* in_sizes, int n_in,
                              void* d_out, int out_size, void* d_ws, size_t ws_size,
                              hipStream_t stream) {
    const float* a0 = (const float*)d_in[0];
    const float* W = (const float*)d_in[1];
    const int* X1 = (const int*)d_in[2];   // int64 in ref -> int32 on device
    const int* X2 = (const int*)d_in[3];
    float* out = (float*)d_out;

    // Split-path ws layout: pi @0 (16384B) | pi1 @16384 | pi2 @16640 |
    // T0 f16x4 @17408 (160,000B) | A1 f16 planes @177,408 (160,000B) |
    // F f16 planes @337,408 (20,480,000B) -> total 20,817,408B.
    const size_t SPLIT_WS = 20817408;
    if (ws_size >= SPLIT_WS) {
        float* pi = (float*)d_ws;
        float* pi1 = pi + 4096;
        float* pi2 = pi1 + 64;
        f16x4* T0 = (f16x4*)((char*)d_ws + 17408);
        _Float16* A1p = (_Float16*)((char*)d_ws + 177408);
        _Float16* F = (_Float16*)((char*)d_ws + 337408);

        softmax_kernel<<<1, 1024, 0, stream>>>(W, pi, pi1, pi2);
        packf16_kernel<<<20, 1024, 0, stream>>>(a0, T0);
        // iter 1
        fclause_kernel<0><<<256, 1024, 0, stream>>>(T0, nullptr, X1, X2, F);
        bilinear_kernel<1><<<dim3(79, 4), 256, 0, stream>>>(F, pi, pi1, pi2,
                                                            a0, nullptr, A1p, nullptr);
        // iter 2
        fclause_kernel<1><<<256, 1024, 0, stream>>>(nullptr, A1p, X1, X2, F);
        bilinear_kernel<2><<<dim3(79, 4), 256, 0, stream>>>(F, pi, pi1, pi2,
                                                            nullptr, A1p, nullptr, out);
        return;
    }

    // ---------- R4 fallback ----------
    const int grid = (NN + 63) / 64;  // 313
    const bool use_ws = (ws_size >= (size_t)177408);
    if (use_ws) {
        float* pi = (float*)d_ws;
        float* pi1 = pi + 4096;
        float* pi2 = pi1 + 64;
        f16x4* at1 = (f16x4*)((char*)d_ws + 17408);
        softmax_kernel<<<1, 1024, 0, stream>>>(W, pi, pi1, pi2);
        iter_kernel<0, 1><<<grid, 1024, 0, stream>>>(a0, nullptr, X1, X2,
                                                     pi, pi1, pi2, nullptr, at1);
        iter_kernel<1, 0><<<grid, 1024, 0, stream>>>(nullptr, at1, X1, X2,
                                                     pi, pi1, pi2, out, nullptr);
    } else {
        float* pi = (float*)d_out;
        float* pi1 = pi + 4096;
        float* pi2 = pi1 + 64;
        f16x4* at1 = (f16x4*)((char*)d_out + 80000);
        f16x4* fin = (f16x4*)((char*)d_out + 240000);
        softmax_kernel<<<1, 1024, 0, stream>>>(W, pi, pi1, pi2);
        iter_kernel<0, 1><<<grid, 1024, 0, stream>>>(a0, nullptr, X1, X2,
                                                     pi, pi1, pi2, nullptr, at1);
        iter_kernel<1, 1><<<grid, 1024, 0, stream>>>(nullptr, at1, X1, X2,
                                                     pi, pi1, pi2, nullptr, fin);
        expand_kernel<<<1, 1024, 0, stream>>>(fin, out);
    }
}

// Round 6
// 316.722 us; speedup vs baseline: 1.1231x; 1.1231x over previous
//
#include <hip/hip_runtime.h>

#define NN 20000

typedef _Float16 f16x2 __attribute__((ext_vector_type(2)));

union U32H2 { unsigned int u; f16x2 h; };

__device__ __forceinline__ f16x2 bc_h2(unsigned int u) { U32H2 x; x.u = u; return x.h; }
__device__ __forceinline__ unsigned int dup_h(float v) {
    _Float16 h = (_Float16)v;
    unsigned short b = __builtin_bit_cast(unsigned short, h);
    return ((unsigned int)b << 16) | b;
}

// DPP float move
template <int CTRL>
__device__ __forceinline__ float dppf(float v) {
    return __builtin_bit_cast(float, __builtin_amdgcn_update_dpp(
        0, __builtin_bit_cast(int, v), CTRL, 0xF, 0xF, true));
}
// max over each aligned 8-lane group (all 8 lanes get the result)
__device__ __forceinline__ float octmaxf(float v) {
    v = fmaxf(v, dppf<0xB1>(v));    // quad_perm xor1
    v = fmaxf(v, dppf<0x4E>(v));    // quad_perm xor2
    v = fmaxf(v, dppf<0x141>(v));   // row_half_mirror (xor4 within 8)
    return v;
}

// ---------------- prep: softmax(W) -> packed-f16 pi tables ----------------
__global__ __launch_bounds__(1024) void prep_kernel(const float* __restrict__ W,
                                                    unsigned int* __restrict__ pi_pk,
                                                    unsigned int* __restrict__ pi1_pk,
                                                    unsigned int* __restrict__ pi2_pk) {
    __shared__ float red[1024];
    __shared__ float piL[4096];
    int t = threadIdx.x;
    float4 wv = ((const float4*)W)[t];
    float m = fmaxf(fmaxf(wv.x, wv.y), fmaxf(wv.z, wv.w));
    red[t] = m; __syncthreads();
    for (int s = 512; s > 0; s >>= 1) {
        if (t < s) red[t] = fmaxf(red[t], red[t + s]);
        __syncthreads();
    }
    m = red[0];
    __syncthreads();
    float e0 = expf(wv.x - m), e1 = expf(wv.y - m);
    float e2 = expf(wv.z - m), e3 = expf(wv.w - m);
    red[t] = e0 + e1 + e2 + e3;
    __syncthreads();
    for (int s = 512; s > 0; s >>= 1) {
        if (t < s) red[t] += red[t + s];
        __syncthreads();
    }
    float inv = 1.0f / red[0];
    float p0 = e0 * inv, p1 = e1 * inv, p2 = e2 * inv, p3 = e3 * inv;
    piL[t * 4 + 0] = p0; piL[t * 4 + 1] = p1;
    piL[t * 4 + 2] = p2; piL[t * 4 + 3] = p3;
    pi_pk[t * 4 + 0] = dup_h(p0);
    pi_pk[t * 4 + 1] = dup_h(p1);
    pi_pk[t * 4 + 2] = dup_h(p2);
    pi_pk[t * 4 + 3] = dup_h(p3);
    __syncthreads();
    if (t < 64) {
        float s = 0.f;
        for (int k = 0; k < 64; k++) s += piL[t * 64 + k];
        pi1_pk[t] = dup_h(s);
    } else if (t < 128) {
        int k = t - 64;
        float s = 0.f;
        for (int j = 0; j < 64; j++) s += piL[j * 64 + k];
        pi2_pk[k] = dup_h(s);
    }
}

// ---------------- pack a0 fp32 (B,N) planes -> u8x4 table ----------------
__global__ __launch_bounds__(1024) void pack_kernel(const float* __restrict__ a0,
                                                    unsigned int* __restrict__ T0) {
    int i = blockIdx.x * 1024 + threadIdx.x;
    if (i < NN) {
        unsigned int b0 = __float2uint_rn(__saturatef(a0[i]) * 255.0f);
        unsigned int b1 = __float2uint_rn(__saturatef(a0[NN + i]) * 255.0f);
        unsigned int b2 = __float2uint_rn(__saturatef(a0[2 * NN + i]) * 255.0f);
        unsigned int b3 = __float2uint_rn(__saturatef(a0[3 * NN + i]) * 255.0f);
        T0[i] = b0 | (b1 << 8) | (b2 << 16) | (b3 << 24);
    }
}

// ---------------- fused predicate_forward iteration ----------------
// 256 blocks x 1024 threads, 1 block/CU (130 KB LDS). Block owns a
// contiguous n-range (79/78), processed as 2 chunks (<=40 n).
// Phase 1: wave wid handles rows {wid+16*rr}; lanes = 8n x 8w; X loads
// 512 B coalesced + 1-deep prefetch; gathers from u8x4 LDS table; DPP
// oct-max over w; F tile (f16, scaled to [0,1]) in LDS.
// Phase 2: thread=(q:8j, bp, n); packed-f16 bilinear, pi via uniform loads.
// ITER=1: aprev = a0 (fp32), dst = u8x4 table T1.
// ITER=2: aprev = u8 table (damped by (1-d)), dst = fp32 (B,N) planes.
template <int ITER>
__global__ __launch_bounds__(1024, 4) void fused_iter(
    const unsigned int* __restrict__ Tsrc,
    const int* __restrict__ X1, const int* __restrict__ X2,
    const unsigned int* __restrict__ pi_pk,
    const unsigned int* __restrict__ pi1_pk,
    const unsigned int* __restrict__ pi2_pk,
    const float* __restrict__ a0,
    unsigned int* __restrict__ Tdst, float* __restrict__ outP) {
    __shared__ unsigned int tab[NN];          // 80,000 B
    __shared__ unsigned int Ft[128][40][2];   // 40,960 B  [row][col][bpair]
    __shared__ float redp[8][64][4];          // 8,192 B   [q][n][b]
    __shared__ float a_sm[64][4];             // 1,024 B

    const int t = threadIdx.x;
    for (int i = t; i < NN; i += 1024) tab[i] = Tsrc[i];

    const int bid = (int)blockIdx.x;
    const int bstart = bid < 32 ? bid * 79 : 32 * 79 + (bid - 32) * 78;
    const int bcnt = bid < 32 ? 79 : 78;
    const int c0 = (bcnt + 1) >> 1;  // 40 or 39

    const int wid = t >> 6, lane = t & 63, ni = lane >> 3, w = lane & 7;
    const int q = t >> 7, bp = (t >> 6) & 1, n_l = t & 63;

    __syncthreads();

    for (int ch = 0; ch < 2; ++ch) {
        const int nb = bstart + (ch ? c0 : 0);
        const int cn = ch ? (bcnt - c0) : c0;

        // ---------------- phase 1 ----------------
        {
            const float sc = 1.0f / 65025.0f;
            int2 qc;
            {
                int r = wid, k = r & 63;
                const int* Xp = (r >> 6) ? X2 : X1;
                int n = nb + ni; int nc = n < NN ? n : NN - 1;
                qc = *(const int2*)(Xp + (((size_t)k * NN + nc) * 8 + w) * 2);
            }
#pragma unroll 4
            for (int s = 0; s < 40; ++s) {
                int2 qn = qc;
                if (s + 1 < 40) {
                    int s1 = s + 1, rr1 = s1 / 5, oc1 = s1 % 5;
                    int r = wid + 16 * rr1, k = r & 63;
                    const int* Xp = (r >> 6) ? X2 : X1;
                    int n = nb + oc1 * 8 + ni; int nc = n < NN ? n : NN - 1;
                    qn = *(const int2*)(Xp + (((size_t)k * NN + nc) * 8 + w) * 2);
                }
                int rr = s / 5, oc = s % 5;
                int r = wid + 16 * rr;
                unsigned int ga = tab[qc.x], gb = tab[qc.y];
                float p0 = (float)(ga & 255u) * (float)(gb & 255u) * sc;
                float p1 = (float)((ga >> 8) & 255u) * (float)((gb >> 8) & 255u) * sc;
                float p2 = (float)((ga >> 16) & 255u) * (float)((gb >> 16) & 255u) * sc;
                float p3 = (float)(ga >> 24) * (float)(gb >> 24) * sc;
                p0 = octmaxf(p0); p1 = octmaxf(p1);
                p2 = octmaxf(p2); p3 = octmaxf(p3);
                int col = oc * 8 + ni;
                if (w == 0 && col < cn) {
                    unsigned int lo, hi;
                    { U32H2 x; x.h = f16x2{(_Float16)p0, (_Float16)p1}; lo = x.u; }
                    { U32H2 x; x.h = f16x2{(_Float16)p2, (_Float16)p3}; hi = x.u; }
                    *(uint2*)&Ft[r][col][0] = make_uint2(lo, hi);
                }
                qc = qn;
            }
        }
        __syncthreads();

        // ---------------- phase 2 ----------------
        {
            float part0 = 0.f, part1 = 0.f;
            if (n_l < cn) {
                f16x2 f2v[64];
#pragma unroll
                for (int k = 0; k < 64; ++k) f2v[k] = bc_h2(Ft[64 + k][n_l][bp]);

                f16x2 zero = {(_Float16)0, (_Float16)0};
                f16x2 euv = zero, eu = zero;
#pragma unroll
                for (int jj = 0; jj < 8; ++jj) {
                    int j = q * 8 + jj;
                    f16x2 f1 = bc_h2(Ft[j][n_l][bp]);
                    const unsigned int* pip = pi_pk + j * 64;  // wave-uniform
                    f16x2 i0 = zero, i1 = zero, i2 = zero, i3 = zero;
#pragma unroll
                    for (int k = 0; k < 64; k += 4) {
                        i0 += bc_h2(pip[k]) * f2v[k];
                        i1 += bc_h2(pip[k + 1]) * f2v[k + 1];
                        i2 += bc_h2(pip[k + 2]) * f2v[k + 2];
                        i3 += bc_h2(pip[k + 3]) * f2v[k + 3];
                    }
                    f16x2 inner = (i0 + i1) + (i2 + i3);
                    euv += f1 * inner;
                    eu += bc_h2(pi1_pk[j]) * f1;
                }
                part0 = (float)eu[0] - (float)euv[0];
                part1 = (float)eu[1] - (float)euv[1];
                if (q == 0) {
                    f16x2 e0 = zero, e1 = zero, e2 = zero, e3 = zero;
#pragma unroll
                    for (int k = 0; k < 64; k += 4) {
                        e0 += bc_h2(pi2_pk[k]) * f2v[k];
                        e1 += bc_h2(pi2_pk[k + 1]) * f2v[k + 1];
                        e2 += bc_h2(pi2_pk[k + 2]) * f2v[k + 2];
                        e3 += bc_h2(pi2_pk[k + 3]) * f2v[k + 3];
                    }
                    f16x2 ev = (e0 + e1) + (e2 + e3);
                    part0 += (float)ev[0];
                    part1 += (float)ev[1];
                }
            }
            *(float2*)&redp[q][n_l][bp * 2] = make_float2(part0, part1);
        }
        __syncthreads();

        // ---------------- combine + soft-OR update ----------------
        if (t < 256) {
            int n = t & 63, b = t >> 6;
            if (n < cn) {
                float d = 0.f;
#pragma unroll
                for (int q8 = 0; q8 < 8; ++q8) d += redp[q8][n][b];
                int gn = nb + n;
                float ap;
                if (ITER == 1) ap = a0[(size_t)b * NN + gn];
                else ap = (float)((tab[gn] >> (8 * b)) & 255u) * (1.0f / 255.0f);
                float an = 1.0f - (1.0f - ap) * (1.0f - d);
                if (ITER == 1) a_sm[n][b] = an;
                else outP[(size_t)b * NN + gn] = an;
            }
        }
        __syncthreads();
        if (ITER == 1 && t < 64 && t < cn) {
            unsigned int b0 = __float2uint_rn(__saturatef(a_sm[t][0]) * 255.0f);
            unsigned int b1 = __float2uint_rn(__saturatef(a_sm[t][1]) * 255.0f);
            unsigned int b2 = __float2uint_rn(__saturatef(a_sm[t][2]) * 255.0f);
            unsigned int b3 = __float2uint_rn(__saturatef(a_sm[t][3]) * 255.0f);
            Tdst[nb + t] = b0 | (b1 << 8) | (b2 << 16) | (b3 << 24);
        }
        __syncthreads();
    }
}

extern "C" void kernel_launch(void* const* d_in, const int* in_sizes, int n_in,
                              void* d_out, int out_size, void* d_ws, size_t ws_size,
                              hipStream_t stream) {
    const float* a0 = (const float*)d_in[0];
    const float* W = (const float*)d_in[1];
    const int* X1 = (const int*)d_in[2];   // int64 in ref -> int32 on device
    const int* X2 = (const int*)d_in[3];
    float* out = (float*)d_out;

    // ws layout: pi_pk @0 (16,384) | pi1_pk @16,384 (256) | pi2_pk @16,640 (256)
    // | T0 @16,896 (80,000) | T1 @96,896 (80,000) -> 176,896 B total.
    if (ws_size < (size_t)176896) return;  // R5 measured ws >= 20.8 MB
    unsigned int* pi_pk = (unsigned int*)d_ws;
    unsigned int* pi1_pk = (unsigned int*)((char*)d_ws + 16384);
    unsigned int* pi2_pk = (unsigned int*)((char*)d_ws + 16640);
    unsigned int* T0 = (unsigned int*)((char*)d_ws + 16896);
    unsigned int* T1 = (unsigned int*)((char*)d_ws + 96896);

    prep_kernel<<<1, 1024, 0, stream>>>(W, pi_pk, pi1_pk, pi2_pk);
    pack_kernel<<<20, 1024, 0, stream>>>(a0, T0);
    fused_iter<1><<<256, 1024, 0, stream>>>(T0, X1, X2, pi_pk, pi1_pk, pi2_pk,
                                            a0, T1, nullptr);
    fused_iter<2><<<256, 1024, 0, stream>>>(T1, X1, X2, pi_pk, pi1_pk, pi2_pk,
                                            nullptr, nullptr, out);
}

// Round 8
// 285.319 us; speedup vs baseline: 1.2467x; 1.1101x over previous
//
#include <hip/hip_runtime.h>

#define NN 20000

typedef _Float16 f16x2 __attribute__((ext_vector_type(2)));
typedef unsigned short u16x2 __attribute__((ext_vector_type(2)));

union U32H2 { unsigned int u; f16x2 h; };
union U32S2 { unsigned int u; u16x2 s; };

__device__ __forceinline__ f16x2 bc_h2(unsigned int u) { U32H2 x; x.u = u; return x.h; }
__device__ __forceinline__ unsigned int dup_h(float v) {
    _Float16 h = (_Float16)v;
    unsigned short b = __builtin_bit_cast(unsigned short, h);
    return ((unsigned int)b << 16) | b;
}
// packed f32->f16 convert, result as raw u32 (v_cvt_pkrtz_f16_f32)
__device__ __forceinline__ unsigned int pkrtz_u32(float a, float b) {
    return __builtin_bit_cast(unsigned int, __builtin_amdgcn_cvt_pkrtz(a, b));
}

// one DPP step + packed-u16 max (v_pk_max_u16)
template <int CTRL>
__device__ __forceinline__ unsigned int pkmax_dpp(unsigned int v) {
    unsigned int d = (unsigned int)__builtin_amdgcn_update_dpp(
        0, (int)v, CTRL, 0xF, 0xF, true);
    U32S2 a, b; a.u = v; b.u = d;
    a.s = __builtin_elementwise_max(a.s, b.s);
    return a.u;
}
// max over each aligned 8-lane group (verified chain from R6)
__device__ __forceinline__ unsigned int octmax_u16x2(unsigned int v) {
    v = pkmax_dpp<0xB1>(v);    // quad_perm xor1
    v = pkmax_dpp<0x4E>(v);    // quad_perm xor2
    v = pkmax_dpp<0x141>(v);   // row_half_mirror (xor4 within 8)
    return v;
}

// ---------------- prep: softmax(W) -> packed-f16 pi tables ----------------
__global__ __launch_bounds__(1024) void prep_kernel(const float* __restrict__ W,
                                                    unsigned int* __restrict__ pi_pk,
                                                    unsigned int* __restrict__ pi_t_pk,
                                                    unsigned int* __restrict__ pi1_pk,
                                                    unsigned int* __restrict__ pi2_pk) {
    __shared__ float red[1024];
    __shared__ float piL[4096];
    int t = threadIdx.x;
    float4 wv = ((const float4*)W)[t];
    float m = fmaxf(fmaxf(wv.x, wv.y), fmaxf(wv.z, wv.w));
    red[t] = m; __syncthreads();
    for (int s = 512; s > 0; s >>= 1) {
        if (t < s) red[t] = fmaxf(red[t], red[t + s]);
        __syncthreads();
    }
    m = red[0];
    __syncthreads();
    float e0 = expf(wv.x - m), e1 = expf(wv.y - m);
    float e2 = expf(wv.z - m), e3 = expf(wv.w - m);
    red[t] = e0 + e1 + e2 + e3;
    __syncthreads();
    for (int s = 512; s > 0; s >>= 1) {
        if (t < s) red[t] += red[t + s];
        __syncthreads();
    }
    float inv = 1.0f / red[0];
    float p[4] = { e0 * inv, e1 * inv, e2 * inv, e3 * inv };
#pragma unroll
    for (int i = 0; i < 4; i++) {
        int f = t * 4 + i;
        piL[f] = p[i];
        unsigned int d = dup_h(p[i]);
        pi_pk[f] = d;
        pi_t_pk[(f & 63) * 64 + (f >> 6)] = d;  // transposed [k][j]
    }
    __syncthreads();
    if (t < 64) {
        float s = 0.f;
        for (int k = 0; k < 64; k++) s += piL[t * 64 + k];
        pi1_pk[t] = dup_h(s);
    } else if (t < 128) {
        int k = t - 64;
        float s = 0.f;
        for (int j = 0; j < 64; j++) s += piL[j * 64 + k];
        pi2_pk[k] = dup_h(s);
    }
}

// ---------------- pack a0 fp32 (B,N) planes -> u8x4 table ----------------
__global__ __launch_bounds__(1024) void pack_kernel(const float* __restrict__ a0,
                                                    unsigned int* __restrict__ T0) {
    int i = blockIdx.x * 1024 + threadIdx.x;
    if (i < NN) {
        unsigned int b0 = __float2uint_rn(__saturatef(a0[i]) * 255.0f);
        unsigned int b1 = __float2uint_rn(__saturatef(a0[NN + i]) * 255.0f);
        unsigned int b2 = __float2uint_rn(__saturatef(a0[2 * NN + i]) * 255.0f);
        unsigned int b3 = __float2uint_rn(__saturatef(a0[3 * NN + i]) * 255.0f);
        T0[i] = b0 | (b1 << 8) | (b2 << 16) | (b3 << 24);
    }
}

// ---------------- fused predicate_forward iteration ----------------
template <int ITER>
__global__ __launch_bounds__(1024, 4) void fused_iter(
    const unsigned int* __restrict__ Tsrc,
    const int* __restrict__ X1, const int* __restrict__ X2,
    const unsigned int* __restrict__ pi_t_pk,
    const unsigned int* __restrict__ pi1_pk,
    const unsigned int* __restrict__ pi2_pk,
    const float* __restrict__ a0,
    unsigned int* __restrict__ Tdst, float* __restrict__ outP) {
    __shared__ unsigned int tab[NN];          // 80,000 B
    __shared__ unsigned int Ft[128][40][2];   // 40,960 B  [row][col][bpair]
    __shared__ float redp[8][64][4];          // 8,192 B
    __shared__ float a_sm[64][4];             // 1,024 B

    const int t = threadIdx.x;
    for (int i = t; i < NN; i += 1024) tab[i] = Tsrc[i];

    const int bid = (int)blockIdx.x;
    const int bstart = bid < 32 ? bid * 79 : 32 * 79 + (bid - 32) * 78;
    const int bcnt = bid < 32 ? 79 : 78;
    const int c0 = (bcnt + 1) >> 1;  // 40 or 39

    const int wid = t >> 6, lane = t & 63, ni = lane >> 3, w = lane & 7;
    const int q = t >> 7, bp = (t >> 6) & 1, n_l = t & 63;

    __syncthreads();

    for (int ch = 0; ch < 2; ++ch) {
        const int nb = bstart + (ch ? c0 : 0);
        const int cn = ch ? (bcnt - c0) : c0;

        // ---------------- phase 1: clause gathers ----------------
        {
            const float sc = 1.0f / 65025.0f;
            int2 q5[5];
            // preload row rr=0 (5 col-groups)
            {
                const int row = wid, k = row & 63;
                const int2* Xq = (const int2*)((row >> 6) ? X2 : X1);
#pragma unroll
                for (int oc = 0; oc < 5; ++oc) {
                    int n = nb + oc * 8 + ni;
                    int nc = n < NN ? n : NN - 1;
                    q5[oc] = Xq[((size_t)k * NN + nc) * 8 + w];
                }
            }
#pragma unroll
            for (int rr = 0; rr < 8; ++rr) {
                int2 qn[5];
                if (rr < 7) {
                    const int row = wid + 16 * (rr + 1), k = row & 63;
                    const int2* Xq = (const int2*)((row >> 6) ? X2 : X1);
#pragma unroll
                    for (int oc = 0; oc < 5; ++oc) {
                        int n = nb + oc * 8 + ni;
                        int nc = n < NN ? n : NN - 1;
                        qn[oc] = Xq[((size_t)k * NN + nc) * 8 + w];
                    }
                }
                const int row = wid + 16 * rr;
                // issue all 10 gathers for this row first
                unsigned int ga[5], gb[5];
#pragma unroll
                for (int oc = 0; oc < 5; ++oc) {
                    ga[oc] = tab[q5[oc].x];
                    gb[oc] = tab[q5[oc].y];
                }
#pragma unroll
                for (int oc = 0; oc < 5; ++oc) {
                    // packed-u16 products: pe=(b0,b2), po=(b1,b3)
                    unsigned int ea = ga[oc] & 0x00FF00FFu;
                    unsigned int oa = (ga[oc] >> 8) & 0x00FF00FFu;
                    unsigned int eb = gb[oc] & 0x00FF00FFu;
                    unsigned int ob = (gb[oc] >> 8) & 0x00FF00FFu;
                    U32S2 pe, po, xb;
                    pe.u = ea; xb.u = eb; pe.s = pe.s * xb.s;
                    po.u = oa; xb.u = ob; po.s = po.s * xb.s;
                    unsigned int peu = octmax_u16x2(pe.u);
                    unsigned int pou = octmax_u16x2(po.u);
                    int col = oc * 8 + ni;
                    if (w == 0 && col < cn) {
                        float f0 = (float)(peu & 0xFFFFu) * sc;   // b0
                        float f1 = (float)(pou & 0xFFFFu) * sc;   // b1
                        float f2 = (float)(peu >> 16) * sc;       // b2
                        float f3 = (float)(pou >> 16) * sc;       // b3
                        unsigned int ul = pkrtz_u32(f0, f1);
                        unsigned int uh = pkrtz_u32(f2, f3);
                        *(uint2*)&Ft[row][col][0] = make_uint2(ul, uh);
                    }
                }
#pragma unroll
                for (int oc = 0; oc < 5; ++oc) q5[oc] = qn[oc];
            }
        }
        __syncthreads();

        // ---------------- phase 2: bilinear (Ft read once per k) ----------------
        {
            float part0 = 0.f, part1 = 0.f;
            if (n_l < cn) {
                f16x2 zero = {(_Float16)0, (_Float16)0};
                f16x2 f1v[8];
                f16x2 eu = zero;
#pragma unroll
                for (int jj = 0; jj < 8; ++jj) {
                    f1v[jj] = bc_h2(Ft[q * 8 + jj][n_l][bp]);
                    eu += bc_h2(pi1_pk[q * 8 + jj]) * f1v[jj];
                }
                f16x2 euv = zero, ev = zero;
#pragma unroll 8
                for (int k = 0; k < 64; ++k) {
                    f16x2 f2 = bc_h2(Ft[64 + k][n_l][bp]);
                    const uint4* pt = (const uint4*)(pi_t_pk + k * 64 + q * 8);
                    uint4 w0 = pt[0], w1 = pt[1];  // wave-uniform -> s_load
                    f16x2 ts = bc_h2(w0.x) * f1v[0] + bc_h2(w0.y) * f1v[1] +
                               bc_h2(w0.z) * f1v[2] + bc_h2(w0.w) * f1v[3] +
                               bc_h2(w1.x) * f1v[4] + bc_h2(w1.y) * f1v[5] +
                               bc_h2(w1.z) * f1v[6] + bc_h2(w1.w) * f1v[7];
                    euv += f2 * ts;
                    if (q == 0) ev += bc_h2(pi2_pk[k]) * f2;
                }
                part0 = (float)eu[0] - (float)euv[0];
                part1 = (float)eu[1] - (float)euv[1];
                if (q == 0) {
                    part0 += (float)ev[0];
                    part1 += (float)ev[1];
                }
            }
            *(float2*)&redp[q][n_l][bp * 2] = make_float2(part0, part1);
        }
        __syncthreads();

        // ---------------- combine + soft-OR update ----------------
        if (t < 256) {
            int n = t & 63, b = t >> 6;
            if (n < cn) {
                float d = 0.f;
#pragma unroll
                for (int q8 = 0; q8 < 8; ++q8) d += redp[q8][n][b];
                int gn = nb + n;
                float ap;
                if (ITER == 1) ap = a0[(size_t)b * NN + gn];
                else ap = (float)((tab[gn] >> (8 * b)) & 255u) * (1.0f / 255.0f);
                float an = 1.0f - (1.0f - ap) * (1.0f - d);
                if (ITER == 1) a_sm[n][b] = an;
                else outP[(size_t)b * NN + gn] = an;
            }
        }
        __syncthreads();
        if (ITER == 1 && t < 64 && t < cn) {
            unsigned int b0 = __float2uint_rn(__saturatef(a_sm[t][0]) * 255.0f);
            unsigned int b1 = __float2uint_rn(__saturatef(a_sm[t][1]) * 255.0f);
            unsigned int b2 = __float2uint_rn(__saturatef(a_sm[t][2]) * 255.0f);
            unsigned int b3 = __float2uint_rn(__saturatef(a_sm[t][3]) * 255.0f);
            Tdst[nb + t] = b0 | (b1 << 8) | (b2 << 16) | (b3 << 24);
        }
        __syncthreads();
    }
}

extern "C" void kernel_launch(void* const* d_in, const int* in_sizes, int n_in,
                              void* d_out, int out_size, void* d_ws, size_t ws_size,
                              hipStream_t stream) {
    const float* a0 = (const float*)d_in[0];
    const float* W = (const float*)d_in[1];
    const int* X1 = (const int*)d_in[2];   // int64 in ref -> int32 on device
    const int* X2 = (const int*)d_in[3];
    float* out = (float*)d_out;

    // ws: pi_pk @0 (16,384) | pi_t_pk @16,384 (16,384) | pi1_pk @32,768 (256)
    // | pi2_pk @33,024 (256) | T0 @33,280 (80,000) | T1 @113,280 (80,000)
    if (ws_size < (size_t)193280) return;  // R5 measured ws >= 20.8 MB
    unsigned int* pi_pk  = (unsigned int*)d_ws;
    unsigned int* pi_t   = (unsigned int*)((char*)d_ws + 16384);
    unsigned int* pi1_pk = (unsigned int*)((char*)d_ws + 32768);
    unsigned int* pi2_pk = (unsigned int*)((char*)d_ws + 33024);
    unsigned int* T0     = (unsigned int*)((char*)d_ws + 33280);
    unsigned int* T1     = (unsigned int*)((char*)d_ws + 113280);

    prep_kernel<<<1, 1024, 0, stream>>>(W, pi_pk, pi_t, pi1_pk, pi2_pk);
    pack_kernel<<<20, 1024, 0, stream>>>(a0, T0);
    fused_iter<1><<<256, 1024, 0, stream>>>(T0, X1, X2, pi_t, pi1_pk, pi2_pk,
                                            a0, T1, nullptr);
    fused_iter<2><<<256, 1024, 0, stream>>>(T1, X1, X2, pi_t, pi1_pk, pi2_pk,
                                            nullptr, nullptr, out);
}

// Round 9
// 249.013 us; speedup vs baseline: 1.4285x; 1.1458x over previous
//
#include <hip/hip_runtime.h>

#define NN 20000

typedef _Float16 f16x2 __attribute__((ext_vector_type(2)));
typedef unsigned short u16x2 __attribute__((ext_vector_type(2)));

union U32H2 { unsigned int u; f16x2 h; };
union U32S2 { unsigned int u; u16x2 s; };

__device__ __forceinline__ f16x2 bc_h2(unsigned int u) { U32H2 x; x.u = u; return x.h; }
__device__ __forceinline__ unsigned int dup_h(float v) {
    _Float16 h = (_Float16)v;
    unsigned short b = __builtin_bit_cast(unsigned short, h);
    return ((unsigned int)b << 16) | b;
}
// packed f32->f16 convert, result as raw u32 (v_cvt_pkrtz_f16_f32)
__device__ __forceinline__ unsigned int pkrtz_u32(float a, float b) {
    return __builtin_bit_cast(unsigned int, __builtin_amdgcn_cvt_pkrtz(a, b));
}

// one DPP step + packed-u16 max (v_pk_max_u16)
template <int CTRL>
__device__ __forceinline__ unsigned int pkmax_dpp(unsigned int v) {
    unsigned int d = (unsigned int)__builtin_amdgcn_update_dpp(
        0, (int)v, CTRL, 0xF, 0xF, true);
    U32S2 a, b; a.u = v; b.u = d;
    a.s = __builtin_elementwise_max(a.s, b.s);
    return a.u;
}
// max over each aligned 8-lane group (verified chain, R6/R8)
__device__ __forceinline__ unsigned int octmax_u16x2(unsigned int v) {
    v = pkmax_dpp<0xB1>(v);    // quad_perm xor1
    v = pkmax_dpp<0x4E>(v);    // quad_perm xor2
    v = pkmax_dpp<0x141>(v);   // row_half_mirror (xor4 within 8)
    return v;
}

// ---------------- prep: softmax(W) -> packed-f16 pi tables ----------------
__global__ __launch_bounds__(1024) void prep_kernel(const float* __restrict__ W,
                                                    unsigned int* __restrict__ pi_pk,
                                                    unsigned int* __restrict__ pi_t_pk,
                                                    unsigned int* __restrict__ pi1_pk,
                                                    unsigned int* __restrict__ pi2_pk) {
    __shared__ float red[1024];
    __shared__ float piL[4096];
    int t = threadIdx.x;
    float4 wv = ((const float4*)W)[t];
    float m = fmaxf(fmaxf(wv.x, wv.y), fmaxf(wv.z, wv.w));
    red[t] = m; __syncthreads();
    for (int s = 512; s > 0; s >>= 1) {
        if (t < s) red[t] = fmaxf(red[t], red[t + s]);
        __syncthreads();
    }
    m = red[0];
    __syncthreads();
    float e0 = expf(wv.x - m), e1 = expf(wv.y - m);
    float e2 = expf(wv.z - m), e3 = expf(wv.w - m);
    red[t] = e0 + e1 + e2 + e3;
    __syncthreads();
    for (int s = 512; s > 0; s >>= 1) {
        if (t < s) red[t] += red[t + s];
        __syncthreads();
    }
    float inv = 1.0f / red[0];
    float p[4] = { e0 * inv, e1 * inv, e2 * inv, e3 * inv };
#pragma unroll
    for (int i = 0; i < 4; i++) {
        int f = t * 4 + i;
        piL[f] = p[i];
        unsigned int d = dup_h(p[i]);
        pi_pk[f] = d;
        pi_t_pk[(f & 63) * 64 + (f >> 6)] = d;  // transposed [k][j]
    }
    __syncthreads();
    if (t < 64) {
        float s = 0.f;
        for (int k = 0; k < 64; k++) s += piL[t * 64 + k];
        pi1_pk[t] = dup_h(s);
    } else if (t < 128) {
        int k = t - 64;
        float s = 0.f;
        for (int j = 0; j < 64; j++) s += piL[j * 64 + k];
        pi2_pk[k] = dup_h(s);
    }
}

// ---------------- pack a0 fp32 (B,N) planes -> u8x4 table ----------------
__global__ __launch_bounds__(1024) void pack_kernel(const float* __restrict__ a0,
                                                    unsigned int* __restrict__ T0) {
    int i = blockIdx.x * 1024 + threadIdx.x;
    if (i < NN) {
        unsigned int b0 = __float2uint_rn(__saturatef(a0[i]) * 255.0f);
        unsigned int b1 = __float2uint_rn(__saturatef(a0[NN + i]) * 255.0f);
        unsigned int b2 = __float2uint_rn(__saturatef(a0[2 * NN + i]) * 255.0f);
        unsigned int b3 = __float2uint_rn(__saturatef(a0[3 * NN + i]) * 255.0f);
        T0[i] = b0 | (b1 << 8) | (b2 << 16) | (b3 << 24);
    }
}

// ---------------- fused predicate_forward iteration ----------------
template <int ITER>
__global__ __launch_bounds__(1024, 4) void fused_iter(
    const unsigned int* __restrict__ Tsrc,
    const int* __restrict__ X1, const int* __restrict__ X2,
    const unsigned int* __restrict__ pi_t_pk,
    const unsigned int* __restrict__ pi1_pk,
    const unsigned int* __restrict__ pi2_pk,
    const float* __restrict__ a0,
    unsigned int* __restrict__ Tdst, float* __restrict__ outP) {
    __shared__ unsigned int tab[NN];          // 80,000 B
    __shared__ unsigned int Ft[128][40][2];   // 40,960 B  [row][col][bpair]
    __shared__ float redp[8][64][4];          // 8,192 B
    __shared__ float a_sm[64][4];             // 1,024 B

    const int t = threadIdx.x;
    for (int i = t; i < NN; i += 1024) tab[i] = Tsrc[i];

    const int bid = (int)blockIdx.x;
    const int bstart = bid < 32 ? bid * 79 : 32 * 79 + (bid - 32) * 78;
    const int bcnt = bid < 32 ? 79 : 78;
    const int c0 = (bcnt + 1) >> 1;  // 40 or 39

    const int wid = t >> 6, lane = t & 63, ni = lane >> 3, w = lane & 7;
    const int q = t >> 7, bp = (t >> 6) & 1, n_l = t & 63;
    // wave-constant values forced into SGPRs (uniformity analysis can't
    // prove t>>6 / t>>7 uniform; without this, pi loads were per-lane VMEM)
    const int widu = __builtin_amdgcn_readfirstlane(wid);
    const int qu = __builtin_amdgcn_readfirstlane(q);

    __syncthreads();

    for (int ch = 0; ch < 2; ++ch) {
        const int nb = bstart + (ch ? c0 : 0);
        const int cn = ch ? (bcnt - c0) : c0;

        // ---------------- phase 1: clause gathers ----------------
        {
            const float sc = 1.0f / 65025.0f;
            // per-lane X byte-offsets for the 5 col-groups (chunk-invariant)
            int loff[5];
#pragma unroll
            for (int oc = 0; oc < 5; ++oc) {
                int n = nb + oc * 8 + ni;
                int nc = n < NN ? n : NN - 1;
                loff[oc] = nc * 64 + w * 8;   // int2 = 8 B, 16 int2 per n
            }
            int2 q5[5];
            {
                const int row = widu, k = row & 63;           // scalar
                const char* Xb = (const char*)((row >> 6) ? X2 : X1)
                               + (unsigned)(k * NN) * 64u;     // scalar base
#pragma unroll
                for (int oc = 0; oc < 5; ++oc)
                    q5[oc] = *(const int2*)(Xb + loff[oc]);
            }
#pragma unroll
            for (int rr = 0; rr < 8; ++rr) {
                int2 qn[5];
                if (rr < 7) {
                    const int row = widu + 16 * (rr + 1), k = row & 63;
                    const char* Xb = (const char*)((row >> 6) ? X2 : X1)
                                   + (unsigned)(k * NN) * 64u;
#pragma unroll
                    for (int oc = 0; oc < 5; ++oc)
                        qn[oc] = *(const int2*)(Xb + loff[oc]);
                }
                const int row = widu + 16 * rr;
                unsigned int ga[5], gb[5];
#pragma unroll
                for (int oc = 0; oc < 5; ++oc) {
                    ga[oc] = tab[q5[oc].x];
                    gb[oc] = tab[q5[oc].y];
                }
#pragma unroll
                for (int oc = 0; oc < 5; ++oc) {
                    // packed-u16 products: pe=(b0,b2), po=(b1,b3)
                    unsigned int ea = ga[oc] & 0x00FF00FFu;
                    unsigned int oa = (ga[oc] >> 8) & 0x00FF00FFu;
                    unsigned int eb = gb[oc] & 0x00FF00FFu;
                    unsigned int ob = (gb[oc] >> 8) & 0x00FF00FFu;
                    U32S2 pe, po, xb;
                    pe.u = ea; xb.u = eb; pe.s = pe.s * xb.s;
                    po.u = oa; xb.u = ob; po.s = po.s * xb.s;
                    unsigned int peu = octmax_u16x2(pe.u);
                    unsigned int pou = octmax_u16x2(po.u);
                    int col = oc * 8 + ni;
                    if (w == 0 && col < cn) {
                        float f0 = (float)(peu & 0xFFFFu) * sc;   // b0
                        float f1 = (float)(pou & 0xFFFFu) * sc;   // b1
                        float f2 = (float)(peu >> 16) * sc;       // b2
                        float f3 = (float)(pou >> 16) * sc;       // b3
                        unsigned int ul = pkrtz_u32(f0, f1);
                        unsigned int uh = pkrtz_u32(f2, f3);
                        *(uint2*)&Ft[row][col][0] = make_uint2(ul, uh);
                    }
                }
#pragma unroll
                for (int oc = 0; oc < 5; ++oc) q5[oc] = qn[oc];
            }
        }
        __syncthreads();

        // ---------------- phase 2: bilinear (Ft read once per k) ----------------
        {
            float part0 = 0.f, part1 = 0.f;
            if (n_l < cn) {
                f16x2 zero = {(_Float16)0, (_Float16)0};
                f16x2 f1v[8];
                f16x2 eu = zero;
#pragma unroll
                for (int jj = 0; jj < 8; ++jj) {
                    f1v[jj] = bc_h2(Ft[qu * 8 + jj][n_l][bp]);
                    eu += bc_h2(pi1_pk[qu * 8 + jj]) * f1v[jj];  // s_load
                }
                f16x2 euv = zero, ev = zero;
#pragma unroll 8
                for (int k = 0; k < 64; ++k) {
                    f16x2 f2 = bc_h2(Ft[64 + k][n_l][bp]);
                    const uint4* pt = (const uint4*)(pi_t_pk + k * 64 + qu * 8);
                    uint4 w0 = pt[0], w1 = pt[1];  // all-scalar addr -> s_load_dwordx4
                    f16x2 ts = bc_h2(w0.x) * f1v[0] + bc_h2(w0.y) * f1v[1] +
                               bc_h2(w0.z) * f1v[2] + bc_h2(w0.w) * f1v[3] +
                               bc_h2(w1.x) * f1v[4] + bc_h2(w1.y) * f1v[5] +
                               bc_h2(w1.z) * f1v[6] + bc_h2(w1.w) * f1v[7];
                    euv += f2 * ts;
                    if (qu == 0) ev += bc_h2(pi2_pk[k]) * f2;
                }
                part0 = (float)eu[0] - (float)euv[0];
                part1 = (float)eu[1] - (float)euv[1];
                if (qu == 0) {
                    part0 += (float)ev[0];
                    part1 += (float)ev[1];
                }
            }
            *(float2*)&redp[q][n_l][bp * 2] = make_float2(part0, part1);
        }
        __syncthreads();

        // ---------------- combine + soft-OR update ----------------
        if (t < 256) {
            int n = t & 63, b = t >> 6;
            if (n < cn) {
                float d = 0.f;
#pragma unroll
                for (int q8 = 0; q8 < 8; ++q8) d += redp[q8][n][b];
                int gn = nb + n;
                float ap;
                if (ITER == 1) ap = a0[(size_t)b * NN + gn];
                else ap = (float)((tab[gn] >> (8 * b)) & 255u) * (1.0f / 255.0f);
                float an = 1.0f - (1.0f - ap) * (1.0f - d);
                if (ITER == 1) a_sm[n][b] = an;
                else outP[(size_t)b * NN + gn] = an;
            }
        }
        __syncthreads();
        if (ITER == 1 && t < 64 && t < cn) {
            unsigned int b0 = __float2uint_rn(__saturatef(a_sm[t][0]) * 255.0f);
            unsigned int b1 = __float2uint_rn(__saturatef(a_sm[t][1]) * 255.0f);
            unsigned int b2 = __float2uint_rn(__saturatef(a_sm[t][2]) * 255.0f);
            unsigned int b3 = __float2uint_rn(__saturatef(a_sm[t][3]) * 255.0f);
            Tdst[nb + t] = b0 | (b1 << 8) | (b2 << 16) | (b3 << 24);
        }
        __syncthreads();
    }
}

extern "C" void kernel_launch(void* const* d_in, const int* in_sizes, int n_in,
                              void* d_out, int out_size, void* d_ws, size_t ws_size,
                              hipStream_t stream) {
    const float* a0 = (const float*)d_in[0];
    const float* W = (const float*)d_in[1];
    const int* X1 = (const int*)d_in[2];   // int64 in ref -> int32 on device
    const int* X2 = (const int*)d_in[3];
    float* out = (float*)d_out;

    // ws: pi_pk @0 (16,384) | pi_t_pk @16,384 (16,384) | pi1_pk @32,768 (256)
    // | pi2_pk @33,024 (256) | T0 @33,280 (80,000) | T1 @113,280 (80,000)
    if (ws_size < (size_t)193280) return;  // R5 measured ws >= 20.8 MB
    unsigned int* pi_pk  = (unsigned int*)d_ws;
    unsigned int* pi_t   = (unsigned int*)((char*)d_ws + 16384);
    unsigned int* pi1_pk = (unsigned int*)((char*)d_ws + 32768);
    unsigned int* pi2_pk = (unsigned int*)((char*)d_ws + 33024);
    unsigned int* T0     = (unsigned int*)((char*)d_ws + 33280);
    unsigned int* T1     = (unsigned int*)((char*)d_ws + 113280);

    prep_kernel<<<1, 1024, 0, stream>>>(W, pi_pk, pi_t, pi1_pk, pi2_pk);
    pack_kernel<<<20, 1024, 0, stream>>>(a0, T0);
    fused_iter<1><<<256, 1024, 0, stream>>>(T0, X1, X2, pi_t, pi1_pk, pi2_pk,
                                            a0, T1, nullptr);
    fused_iter<2><<<256, 1024, 0, stream>>>(T1, X1, X2, pi_t, pi1_pk, pi2_pk,
                                            nullptr, nullptr, out);
}